// Round 1
// baseline (796.309 us; speedup 1.0000x reference)
//
#include <hip/hip_runtime.h>

#define NN 100000
#define EE 600000
#define GG 1000
#define NB ((NN + 255) / 256)   // 391 blocks for node-sized scans

// ---------------- setup kernels (CSR build + norm) ----------------

__global__ void k_init(int* cnt, int* fillc, float* psum, float* pcnt) {
  int i = blockIdx.x * 256 + threadIdx.x;
  if (i < NN) { cnt[i] = 0; fillc[i] = 0; }
  if (i < GG * 128) psum[i] = 0.f;
  if (i < GG) pcnt[i] = 0.f;
}

__global__ void k_count(const int* __restrict__ dst, int* cnt) {
  int e = blockIdx.x * 256 + threadIdx.x;
  if (e < EE) atomicAdd(&cnt[dst[e]], 1);
}

__global__ void k_dinv(const int* __restrict__ cnt, float* dinv) {
  int i = blockIdx.x * 256 + threadIdx.x;
  if (i < NN) dinv[i] = rsqrtf((float)(cnt[i] + 1));  // +1 = self loop; deg>=1 always
}

__global__ void k_scan1(const int* __restrict__ cnt, int* rowptr, int* bsum) {
  __shared__ int s[256];
  int tid = threadIdx.x;
  int i = blockIdx.x * 256 + tid;
  int v = (i < NN) ? cnt[i] : 0;
  s[tid] = v;
  __syncthreads();
  for (int off = 1; off < 256; off <<= 1) {
    int t = (tid >= off) ? s[tid - off] : 0;
    __syncthreads();
    s[tid] += t;
    __syncthreads();
  }
  if (i < NN) rowptr[i] = s[tid] - v;          // block-local exclusive
  if (tid == 255) bsum[blockIdx.x] = s[255];   // block total
}

__global__ void k_scan2(int* bsum) {
  __shared__ int s[512];
  int tid = threadIdx.x;
  int v = (tid < NB) ? bsum[tid] : 0;
  s[tid] = v;
  __syncthreads();
  for (int off = 1; off < 512; off <<= 1) {
    int t = (tid >= off) ? s[tid - off] : 0;
    __syncthreads();
    s[tid] += t;
    __syncthreads();
  }
  if (tid < NB) bsum[tid] = s[tid] - v;        // exclusive over block sums
}

__global__ void k_scan3(int* rowptr, const int* __restrict__ bsum) {
  int i = blockIdx.x * 256 + threadIdx.x;
  if (i < NN) rowptr[i] += bsum[blockIdx.x];
  if (i == 0) rowptr[NN] = EE;                 // total edge count is fixed
}

__global__ void k_fill(const int* __restrict__ src, const int* __restrict__ dst,
                       const int* __restrict__ rowptr, int* fillc,
                       const float* __restrict__ dinv,
                       int* csr_src, float* csr_w) {
  int e = blockIdx.x * 256 + threadIdx.x;
  if (e >= EE) return;
  int s = src[e], d = dst[e];
  int pos = rowptr[d] + atomicAdd(&fillc[d], 1);
  csr_src[pos] = s;
  csr_w[pos] = dinv[s] * dinv[d];
}

// ---------------- layer kernels ----------------

// layer-0 linear: [N,4] @ [4,128] -> hout (no bias; bias added in aggregate)
__global__ void k_mm0(const float* __restrict__ x, const float* __restrict__ W0,
                      float* __restrict__ hout) {
  int idx = blockIdx.x * 256 + threadIdx.x;
  if (idx >= NN * 128) return;
  int node = idx >> 7, j = idx & 127;
  const float* xr = x + node * 4;
  float s = xr[0] * W0[j];
  s = fmaf(xr[1], W0[128 + j], s);
  s = fmaf(xr[2], W0[256 + j], s);
  s = fmaf(xr[3], W0[384 + j], s);
  hout[idx] = s;
}

// [N,128] @ [128,128], relu applied to the INPUT (prev layer pre-activation)
__global__ __launch_bounds__(256) void k_mm128(const float* __restrict__ hin,
                                               const float* __restrict__ W,
                                               float* __restrict__ hout) {
  __shared__ float As[64][128];   // 32 KB: full K for 64 rows
  int tid = threadIdx.x;
  int row0 = blockIdx.x * 64;
  // cooperative load of A tile with fused relu, float4-coalesced
  #pragma unroll
  for (int t = 0; t < 8; ++t) {
    int idx = t * 1024 + tid * 4;     // 0..8191
    int r = idx >> 7, c = idx & 127;
    int gr = row0 + r;
    float4 v = make_float4(0.f, 0.f, 0.f, 0.f);
    if (gr < NN) v = *(const float4*)(hin + gr * 128 + c);
    v.x = fmaxf(v.x, 0.f); v.y = fmaxf(v.y, 0.f);
    v.z = fmaxf(v.z, 0.f); v.w = fmaxf(v.w, 0.f);
    *(float4*)&As[r][c] = v;
  }
  __syncthreads();
  int ct = tid & 31;      // 32 col-threads * 4 cols = 128 cols
  int rt = tid >> 5;      // 8 row groups * 8 rows = 64 rows
  float acc[8][4];
  #pragma unroll
  for (int i = 0; i < 8; ++i)
    #pragma unroll
    for (int j = 0; j < 4; ++j) acc[i][j] = 0.f;
  #pragma unroll 4
  for (int k = 0; k < 128; ++k) {
    float4 b = *(const float4*)(W + k * 128 + ct * 4);  // coalesced, L1/L2-hot
    #pragma unroll
    for (int i = 0; i < 8; ++i) {
      float a = As[rt * 8 + i][k];   // 2 addrs/wave on one bank = free 2-way
      acc[i][0] = fmaf(a, b.x, acc[i][0]);
      acc[i][1] = fmaf(a, b.y, acc[i][1]);
      acc[i][2] = fmaf(a, b.z, acc[i][2]);
      acc[i][3] = fmaf(a, b.w, acc[i][3]);
    }
  }
  #pragma unroll
  for (int i = 0; i < 8; ++i) {
    int gr = row0 + rt * 8 + i;
    if (gr < NN)
      *(float4*)(hout + gr * 128 + ct * 4) =
          make_float4(acc[i][0], acc[i][1], acc[i][2], acc[i][3]);
  }
}

// out[i] = b + dinv[i]^2 * hlin[i] + sum_e w[e] * hlin[csr_src[e]]
// one wave per node, float2 per lane (64*2 = 128 cols)
__global__ __launch_bounds__(256) void k_aggregate(const float* __restrict__ hlin,
                                                   const int* __restrict__ rowptr,
                                                   const int* __restrict__ csr_src,
                                                   const float* __restrict__ csr_w,
                                                   const float* __restrict__ dinv,
                                                   const float* __restrict__ bias,
                                                   float* __restrict__ hout) {
  int node = blockIdx.x * 4 + (threadIdx.x >> 6);
  int lane = threadIdx.x & 63;
  if (node >= NN) return;
  float di = dinv[node];
  float sw = di * di;
  float2 hv = *(const float2*)(hlin + node * 128 + lane * 2);
  float2 bv = *(const float2*)(bias + lane * 2);
  float2 acc = make_float2(fmaf(sw, hv.x, bv.x), fmaf(sw, hv.y, bv.y));
  int beg = rowptr[node], end = rowptr[node + 1];
  for (int e = beg; e < end; ++e) {
    int s = csr_src[e];      // wave-uniform broadcast load
    float w = csr_w[e];
    float2 v = *(const float2*)(hlin + s * 128 + lane * 2);  // 512B coalesced row
    acc.x = fmaf(w, v.x, acc.x);
    acc.y = fmaf(w, v.y, acc.y);
  }
  *(float2*)(hout + node * 128 + lane * 2) = acc;
}

// ---------------- pooling + MLP head ----------------

__global__ void k_pool(const float* __restrict__ h4, const int* __restrict__ batch,
                       float* psum, float* pcnt) {
  int idx = blockIdx.x * 256 + threadIdx.x;
  if (idx >= NN * 128) return;
  int node = idx >> 7, j = idx & 127;
  int g = batch[node];
  float v = fmaxf(h4[idx], 0.f);    // relu of layer-4 output
  atomicAdd(&psum[g * 128 + j], v);
  if (j == 0) atomicAdd(&pcnt[g], 1.f);
}

__global__ __launch_bounds__(64) void k_mlp(const float* __restrict__ psum,
                                            const float* __restrict__ pcnt,
                                            const float* __restrict__ xs,
                                            const float* __restrict__ Wl1,
                                            const float* __restrict__ bl1,
                                            const float* __restrict__ Wl2,
                                            const float* __restrict__ bl2,
                                            float* __restrict__ out) {
  int g = blockIdx.x;
  int j = threadIdx.x;  // 0..63 hidden units, one wave
  float sc = 1.f / fmaxf(pcnt[g], 1.f);
  float hj = bl1[j];
  const float* ps = psum + g * 128;
  #pragma unroll 4
  for (int k = 0; k < 128; ++k) hj = fmaf(ps[k] * sc, Wl1[k * 64 + j], hj);
  const float* xr = xs + g * 4;
  #pragma unroll
  for (int k = 0; k < 4; ++k) hj = fmaf(xr[k], Wl1[(128 + k) * 64 + j], hj);
  hj = fmaxf(hj, 0.f);
  float val = hj * Wl2[j];
  #pragma unroll
  for (int off = 32; off > 0; off >>= 1) val += __shfl_down(val, off);
  if (j == 0) out[g] = val + bl2[0];
}

// ---------------- launcher ----------------

extern "C" void kernel_launch(void* const* d_in, const int* in_sizes, int n_in,
                              void* d_out, int out_size, void* d_ws, size_t ws_size,
                              hipStream_t stream) {
  const float* x    = (const float*)d_in[0];
  const int*   ei   = (const int*)d_in[1];
  const float* xs   = (const float*)d_in[2];
  const int*   batch= (const int*)d_in[3];
  const float* W0   = (const float*)d_in[4];
  const float* b0   = (const float*)d_in[5];
  const float* W1   = (const float*)d_in[6];
  const float* b1   = (const float*)d_in[7];
  const float* W2   = (const float*)d_in[8];
  const float* b2   = (const float*)d_in[9];
  const float* W3   = (const float*)d_in[10];
  const float* b3   = (const float*)d_in[11];
  const float* Wl1  = (const float*)d_in[12];
  const float* bl1  = (const float*)d_in[13];
  const float* Wl2  = (const float*)d_in[14];
  const float* bl2  = (const float*)d_in[15];
  const int* srcA = ei;        // edge_index[0]
  const int* dstA = ei + EE;   // edge_index[1]
  float* out = (float*)d_out;

  char* p = (char*)d_ws;
  auto take = [&](size_t bytes) { char* q = p; p += (bytes + 255) & ~(size_t)255; return q; };
  float* hA    = (float*)take((size_t)NN * 128 * 4);
  float* hB    = (float*)take((size_t)NN * 128 * 4);
  int*   cnt   = (int*)take((size_t)NN * 4);
  float* dinv  = (float*)take((size_t)NN * 4);
  int*   rowptr= (int*)take((size_t)(NN + 1) * 4);
  int*   fillc = (int*)take((size_t)NN * 4);
  int*   csr_s = (int*)take((size_t)EE * 4);
  float* csr_w = (float*)take((size_t)EE * 4);
  int*   bsum  = (int*)take(512 * 4);
  float* psum  = (float*)take((size_t)GG * 128 * 4);
  float* pcnt  = (float*)take((size_t)GG * 4);

  // setup: degree, norm, CSR-by-dst
  k_init<<<(GG * 128 + 255) / 256, 256, 0, stream>>>(cnt, fillc, psum, pcnt);
  k_count<<<(EE + 255) / 256, 256, 0, stream>>>(dstA, cnt);
  k_dinv<<<NB, 256, 0, stream>>>(cnt, dinv);
  k_scan1<<<NB, 256, 0, stream>>>(cnt, rowptr, bsum);
  k_scan2<<<1, 512, 0, stream>>>(bsum);
  k_scan3<<<NB, 256, 0, stream>>>(rowptr, bsum);
  k_fill<<<(EE + 255) / 256, 256, 0, stream>>>(srcA, dstA, rowptr, fillc, dinv, csr_s, csr_w);

  // layer 0: x @ W0 -> hA; aggregate(hA) + b0 -> hB (pre-relu)
  k_mm0<<<(NN * 128 + 255) / 256, 256, 0, stream>>>(x, W0, hA);
  k_aggregate<<<(NN + 3) / 4, 256, 0, stream>>>(hA, rowptr, csr_s, csr_w, dinv, b0, hB);
  // layers 1-3: relu fused into matmul A-load
  k_mm128<<<(NN + 63) / 64, 256, 0, stream>>>(hB, W1, hA);
  k_aggregate<<<(NN + 3) / 4, 256, 0, stream>>>(hA, rowptr, csr_s, csr_w, dinv, b1, hB);
  k_mm128<<<(NN + 63) / 64, 256, 0, stream>>>(hB, W2, hA);
  k_aggregate<<<(NN + 3) / 4, 256, 0, stream>>>(hA, rowptr, csr_s, csr_w, dinv, b2, hB);
  k_mm128<<<(NN + 63) / 64, 256, 0, stream>>>(hB, W3, hA);
  k_aggregate<<<(NN + 3) / 4, 256, 0, stream>>>(hA, rowptr, csr_s, csr_w, dinv, b3, hB);

  // pool (relu fused) + head MLP
  k_pool<<<(NN * 128 + 255) / 256, 256, 0, stream>>>(hB, batch, psum, pcnt);
  k_mlp<<<GG, 64, 0, stream>>>(psum, pcnt, xs, Wl1, bl1, Wl2, bl2, out);
}

// Round 2
// 643.458 us; speedup vs baseline: 1.2375x; 1.2375x over previous
//
#include <hip/hip_runtime.h>

#define NN 100000
#define EE 600000
#define GG 1000
#define NB ((NN + 255) / 256)   // 391 blocks for node-sized scans

// ---------------- setup kernels (CSR build + norm) ----------------

__global__ void k_init(int* cnt, int* fillc, int* gstart) {
  int i = blockIdx.x * 256 + threadIdx.x;
  if (i < NN) { cnt[i] = 0; fillc[i] = 0; }
  if (i <= GG) gstart[i] = NN;   // default: empty graphs past the last batch id
}

__global__ void k_count(const int* __restrict__ dst, int* cnt) {
  int e = blockIdx.x * 256 + threadIdx.x;
  if (e < EE) atomicAdd(&cnt[dst[e]], 1);
}

__global__ void k_dinv(const int* __restrict__ cnt, float* dinv) {
  int i = blockIdx.x * 256 + threadIdx.x;
  if (i < NN) dinv[i] = rsqrtf((float)(cnt[i] + 1));  // +1 = self loop; deg>=1 always
}

__global__ void k_scan1(const int* __restrict__ cnt, int* rowptr, int* bsum) {
  __shared__ int s[256];
  int tid = threadIdx.x;
  int i = blockIdx.x * 256 + tid;
  int v = (i < NN) ? cnt[i] : 0;
  s[tid] = v;
  __syncthreads();
  for (int off = 1; off < 256; off <<= 1) {
    int t = (tid >= off) ? s[tid - off] : 0;
    __syncthreads();
    s[tid] += t;
    __syncthreads();
  }
  if (i < NN) rowptr[i] = s[tid] - v;          // block-local exclusive
  if (tid == 255) bsum[blockIdx.x] = s[255];   // block total
}

__global__ void k_scan2(int* bsum) {
  __shared__ int s[512];
  int tid = threadIdx.x;
  int v = (tid < NB) ? bsum[tid] : 0;
  s[tid] = v;
  __syncthreads();
  for (int off = 1; off < 512; off <<= 1) {
    int t = (tid >= off) ? s[tid - off] : 0;
    __syncthreads();
    s[tid] += t;
    __syncthreads();
  }
  if (tid < NB) bsum[tid] = s[tid] - v;        // exclusive over block sums
}

__global__ void k_scan3(int* rowptr, const int* __restrict__ bsum) {
  int i = blockIdx.x * 256 + threadIdx.x;
  if (i < NN) rowptr[i] += bsum[blockIdx.x];
  if (i == 0) rowptr[NN] = EE;                 // total edge count is fixed
}

__global__ void k_fill(const int* __restrict__ src, const int* __restrict__ dst,
                       const int* __restrict__ rowptr, int* fillc,
                       const float* __restrict__ dinv,
                       int* csr_src, float* csr_w) {
  int e = blockIdx.x * 256 + threadIdx.x;
  if (e >= EE) return;
  int s = src[e], d = dst[e];
  int pos = rowptr[d] + atomicAdd(&fillc[d], 1);
  csr_src[pos] = s;
  csr_w[pos] = dinv[s] * dinv[d];
}

// batch is sorted: gstart[g] = first node index with batch >= g (boundary scan)
__global__ void k_gbound(const int* __restrict__ batch, int* gstart) {
  int i = blockIdx.x * 256 + threadIdx.x;
  if (i >= NN) return;
  int b = batch[i];
  if (i == 0) {
    for (int g = 0; g <= b; ++g) gstart[g] = 0;
  } else {
    int prev = batch[i - 1];
    for (int g = prev + 1; g <= b; ++g) gstart[g] = i;  // covers empty graphs too
  }
}

// ---------------- layer kernels ----------------

// layer-0 linear: [N,4] @ [4,128] -> hout (no bias; bias added in aggregate)
__global__ void k_mm0(const float* __restrict__ x, const float* __restrict__ W0,
                      float* __restrict__ hout) {
  int idx = blockIdx.x * 256 + threadIdx.x;
  if (idx >= NN * 128) return;
  int node = idx >> 7, j = idx & 127;
  const float* xr = x + node * 4;
  float s = xr[0] * W0[j];
  s = fmaf(xr[1], W0[128 + j], s);
  s = fmaf(xr[2], W0[256 + j], s);
  s = fmaf(xr[3], W0[384 + j], s);
  hout[idx] = s;
}

// [N,128] @ [128,128], relu applied to the INPUT (prev layer pre-activation)
__global__ __launch_bounds__(256) void k_mm128(const float* __restrict__ hin,
                                               const float* __restrict__ W,
                                               float* __restrict__ hout) {
  __shared__ float As[64][128];   // 32 KB: full K for 64 rows
  int tid = threadIdx.x;
  int row0 = blockIdx.x * 64;
  #pragma unroll
  for (int t = 0; t < 8; ++t) {
    int idx = t * 1024 + tid * 4;     // 0..8191
    int r = idx >> 7, c = idx & 127;
    int gr = row0 + r;
    float4 v = make_float4(0.f, 0.f, 0.f, 0.f);
    if (gr < NN) v = *(const float4*)(hin + gr * 128 + c);
    v.x = fmaxf(v.x, 0.f); v.y = fmaxf(v.y, 0.f);
    v.z = fmaxf(v.z, 0.f); v.w = fmaxf(v.w, 0.f);
    *(float4*)&As[r][c] = v;
  }
  __syncthreads();
  int ct = tid & 31;      // 32 col-threads * 4 cols = 128 cols
  int rt = tid >> 5;      // 8 row groups * 8 rows = 64 rows
  float acc[8][4];
  #pragma unroll
  for (int i = 0; i < 8; ++i)
    #pragma unroll
    for (int j = 0; j < 4; ++j) acc[i][j] = 0.f;
  #pragma unroll 4
  for (int k = 0; k < 128; ++k) {
    float4 b = *(const float4*)(W + k * 128 + ct * 4);  // coalesced, L1/L2-hot
    #pragma unroll
    for (int i = 0; i < 8; ++i) {
      float a = As[rt * 8 + i][k];   // 2 addrs/wave on one bank = free 2-way
      acc[i][0] = fmaf(a, b.x, acc[i][0]);
      acc[i][1] = fmaf(a, b.y, acc[i][1]);
      acc[i][2] = fmaf(a, b.z, acc[i][2]);
      acc[i][3] = fmaf(a, b.w, acc[i][3]);
    }
  }
  #pragma unroll
  for (int i = 0; i < 8; ++i) {
    int gr = row0 + rt * 8 + i;
    if (gr < NN)
      *(float4*)(hout + gr * 128 + ct * 4) =
          make_float4(acc[i][0], acc[i][1], acc[i][2], acc[i][3]);
  }
}

// out[i] = b + dinv[i]^2 * hlin[i] + sum_e w[e] * hlin[csr_src[e]]
// one wave per node, float2 per lane (64*2 = 128 cols)
__global__ __launch_bounds__(256) void k_aggregate(const float* __restrict__ hlin,
                                                   const int* __restrict__ rowptr,
                                                   const int* __restrict__ csr_src,
                                                   const float* __restrict__ csr_w,
                                                   const float* __restrict__ dinv,
                                                   const float* __restrict__ bias,
                                                   float* __restrict__ hout) {
  int node = blockIdx.x * 4 + (threadIdx.x >> 6);
  int lane = threadIdx.x & 63;
  if (node >= NN) return;
  float di = dinv[node];
  float sw = di * di;
  float2 hv = *(const float2*)(hlin + node * 128 + lane * 2);
  float2 bv = *(const float2*)(bias + lane * 2);
  float2 acc = make_float2(fmaf(sw, hv.x, bv.x), fmaf(sw, hv.y, bv.y));
  int beg = rowptr[node], end = rowptr[node + 1];
  for (int e = beg; e < end; ++e) {
    int s = csr_src[e];      // wave-uniform broadcast load
    float w = csr_w[e];
    float2 v = *(const float2*)(hlin + s * 128 + lane * 2);  // 512B coalesced row
    acc.x = fmaf(w, v.x, acc.x);
    acc.y = fmaf(w, v.y, acc.y);
  }
  *(float2*)(hout + node * 128 + lane * 2) = acc;
}

// ---------------- fused pool (segmented, no atomics) + MLP head ----------------
// one block per graph; batch is sorted so nodes [gstart[g], gstart[g+1]) belong to g
__global__ __launch_bounds__(256) void k_poolmlp(const float* __restrict__ h4,
                                                 const int* __restrict__ gstart,
                                                 const float* __restrict__ xs,
                                                 const float* __restrict__ Wl1,
                                                 const float* __restrict__ bl1,
                                                 const float* __restrict__ Wl2,
                                                 const float* __restrict__ bl2,
                                                 float* __restrict__ out) {
  __shared__ float4 part[8][32];
  __shared__ float pooled[128];
  int g = blockIdx.x;
  int beg = gstart[g], end = gstart[g + 1];
  int tid = threadIdx.x;
  int cg = tid & 31;        // float4 column group (32 * 4 = 128 cols)
  int rg = tid >> 5;        // 8 rows per iteration
  float4 acc = make_float4(0.f, 0.f, 0.f, 0.f);
  for (int i = beg + rg; i < end; i += 8) {
    float4 v = *(const float4*)(h4 + (size_t)i * 128 + cg * 4);  // 4KB/iter coalesced
    acc.x += fmaxf(v.x, 0.f); acc.y += fmaxf(v.y, 0.f);
    acc.z += fmaxf(v.z, 0.f); acc.w += fmaxf(v.w, 0.f);
  }
  part[rg][cg] = acc;
  __syncthreads();
  if (tid < 32) {
    float4 s = part[0][tid];
    #pragma unroll
    for (int r = 1; r < 8; ++r) {
      float4 v = part[r][tid];
      s.x += v.x; s.y += v.y; s.z += v.z; s.w += v.w;
    }
    float sc = 1.f / fmaxf((float)(end - beg), 1.f);
    pooled[tid * 4 + 0] = s.x * sc;
    pooled[tid * 4 + 1] = s.y * sc;
    pooled[tid * 4 + 2] = s.z * sc;
    pooled[tid * 4 + 3] = s.w * sc;
  }
  __syncthreads();
  if (tid < 64) {   // exactly wave 0
    float hj = bl1[tid];
    #pragma unroll 4
    for (int k = 0; k < 128; ++k) hj = fmaf(pooled[k], Wl1[k * 64 + tid], hj);
    const float* xr = xs + g * 4;
    #pragma unroll
    for (int k = 0; k < 4; ++k) hj = fmaf(xr[k], Wl1[(128 + k) * 64 + tid], hj);
    hj = fmaxf(hj, 0.f);
    float val = hj * Wl2[tid];
    #pragma unroll
    for (int off = 32; off > 0; off >>= 1) val += __shfl_down(val, off);
    if (tid == 0) out[g] = val + bl2[0];
  }
}

// ---------------- launcher ----------------

extern "C" void kernel_launch(void* const* d_in, const int* in_sizes, int n_in,
                              void* d_out, int out_size, void* d_ws, size_t ws_size,
                              hipStream_t stream) {
  const float* x    = (const float*)d_in[0];
  const int*   ei   = (const int*)d_in[1];
  const float* xs   = (const float*)d_in[2];
  const int*   batch= (const int*)d_in[3];
  const float* W0   = (const float*)d_in[4];
  const float* b0   = (const float*)d_in[5];
  const float* W1   = (const float*)d_in[6];
  const float* b1   = (const float*)d_in[7];
  const float* W2   = (const float*)d_in[8];
  const float* b2   = (const float*)d_in[9];
  const float* W3   = (const float*)d_in[10];
  const float* b3   = (const float*)d_in[11];
  const float* Wl1  = (const float*)d_in[12];
  const float* bl1  = (const float*)d_in[13];
  const float* Wl2  = (const float*)d_in[14];
  const float* bl2  = (const float*)d_in[15];
  const int* srcA = ei;        // edge_index[0]
  const int* dstA = ei + EE;   // edge_index[1]
  float* out = (float*)d_out;

  char* p = (char*)d_ws;
  auto take = [&](size_t bytes) { char* q = p; p += (bytes + 255) & ~(size_t)255; return q; };
  float* hA    = (float*)take((size_t)NN * 128 * 4);
  float* hB    = (float*)take((size_t)NN * 128 * 4);
  int*   cnt   = (int*)take((size_t)NN * 4);
  float* dinv  = (float*)take((size_t)NN * 4);
  int*   rowptr= (int*)take((size_t)(NN + 1) * 4);
  int*   fillc = (int*)take((size_t)NN * 4);
  int*   csr_s = (int*)take((size_t)EE * 4);
  float* csr_w = (float*)take((size_t)EE * 4);
  int*   bsum  = (int*)take(512 * 4);
  int*   gstart= (int*)take((size_t)(GG + 1) * 4);

  // setup: degree, norm, CSR-by-dst, graph boundaries
  k_init<<<NB, 256, 0, stream>>>(cnt, fillc, gstart);
  k_count<<<(EE + 255) / 256, 256, 0, stream>>>(dstA, cnt);
  k_dinv<<<NB, 256, 0, stream>>>(cnt, dinv);
  k_scan1<<<NB, 256, 0, stream>>>(cnt, rowptr, bsum);
  k_scan2<<<1, 512, 0, stream>>>(bsum);
  k_scan3<<<NB, 256, 0, stream>>>(rowptr, bsum);
  k_fill<<<(EE + 255) / 256, 256, 0, stream>>>(srcA, dstA, rowptr, fillc, dinv, csr_s, csr_w);
  k_gbound<<<NB, 256, 0, stream>>>(batch, gstart);

  // layer 0: x @ W0 -> hA; aggregate(hA) + b0 -> hB (pre-relu)
  k_mm0<<<(NN * 128 + 255) / 256, 256, 0, stream>>>(x, W0, hA);
  k_aggregate<<<(NN + 3) / 4, 256, 0, stream>>>(hA, rowptr, csr_s, csr_w, dinv, b0, hB);
  // layers 1-3: relu fused into matmul A-load
  k_mm128<<<(NN + 63) / 64, 256, 0, stream>>>(hB, W1, hA);
  k_aggregate<<<(NN + 3) / 4, 256, 0, stream>>>(hA, rowptr, csr_s, csr_w, dinv, b1, hB);
  k_mm128<<<(NN + 63) / 64, 256, 0, stream>>>(hB, W2, hA);
  k_aggregate<<<(NN + 3) / 4, 256, 0, stream>>>(hA, rowptr, csr_s, csr_w, dinv, b2, hB);
  k_mm128<<<(NN + 63) / 64, 256, 0, stream>>>(hB, W3, hA);
  k_aggregate<<<(NN + 3) / 4, 256, 0, stream>>>(hA, rowptr, csr_s, csr_w, dinv, b3, hB);

  // fused pool + head MLP (no atomics)
  k_poolmlp<<<GG, 256, 0, stream>>>(hB, gstart, xs, Wl1, bl1, Wl2, bl2, out);
}

// Round 3
// 562.406 us; speedup vs baseline: 1.4159x; 1.1441x over previous
//
#include <hip/hip_runtime.h>

#define NN 100000
#define EE 600000
#define GG 1000
#define NB ((NN + 255) / 256)   // 391 blocks for node-sized scans

// ---------------- setup kernels (CSR build + norm) ----------------

__global__ void k_init(int* cnt, int* fillc, int* gstart) {
  int i = blockIdx.x * 256 + threadIdx.x;
  if (i < NN) { cnt[i] = 0; fillc[i] = 0; }
  if (i <= GG) gstart[i] = NN;   // default: empty graphs past the last batch id
}

__global__ void k_count(const int* __restrict__ dst, int* cnt) {
  int e = blockIdx.x * 256 + threadIdx.x;
  if (e < EE) atomicAdd(&cnt[dst[e]], 1);
}

__global__ void k_dinv(const int* __restrict__ cnt, float* dinv) {
  int i = blockIdx.x * 256 + threadIdx.x;
  if (i < NN) dinv[i] = rsqrtf((float)(cnt[i] + 1));  // +1 = self loop; deg>=1 always
}

__global__ void k_scan1(const int* __restrict__ cnt, int* rowptr, int* bsum) {
  __shared__ int s[256];
  int tid = threadIdx.x;
  int i = blockIdx.x * 256 + tid;
  int v = (i < NN) ? cnt[i] : 0;
  s[tid] = v;
  __syncthreads();
  for (int off = 1; off < 256; off <<= 1) {
    int t = (tid >= off) ? s[tid - off] : 0;
    __syncthreads();
    s[tid] += t;
    __syncthreads();
  }
  if (i < NN) rowptr[i] = s[tid] - v;          // block-local exclusive
  if (tid == 255) bsum[blockIdx.x] = s[255];   // block total
}

__global__ void k_scan2(int* bsum) {
  __shared__ int s[512];
  int tid = threadIdx.x;
  int v = (tid < NB) ? bsum[tid] : 0;
  s[tid] = v;
  __syncthreads();
  for (int off = 1; off < 512; off <<= 1) {
    int t = (tid >= off) ? s[tid - off] : 0;
    __syncthreads();
    s[tid] += t;
    __syncthreads();
  }
  if (tid < NB) bsum[tid] = s[tid] - v;        // exclusive over block sums
}

__global__ void k_scan3(int* rowptr, const int* __restrict__ bsum) {
  int i = blockIdx.x * 256 + threadIdx.x;
  if (i < NN) rowptr[i] += bsum[blockIdx.x];
  if (i == 0) rowptr[NN] = EE;                 // total edge count is fixed
}

__global__ void k_fill(const int* __restrict__ src, const int* __restrict__ dst,
                       const int* __restrict__ rowptr, int* fillc,
                       const float* __restrict__ dinv,
                       int* csr_src, float* csr_w) {
  int e = blockIdx.x * 256 + threadIdx.x;
  if (e >= EE) return;
  int s = src[e], d = dst[e];
  int pos = rowptr[d] + atomicAdd(&fillc[d], 1);
  csr_src[pos] = s;
  csr_w[pos] = dinv[s] * dinv[d];
}

// batch is sorted: gstart[g] = first node index with batch >= g (boundary scan)
__global__ void k_gbound(const int* __restrict__ batch, int* gstart) {
  int i = blockIdx.x * 256 + threadIdx.x;
  if (i >= NN) return;
  int b = batch[i];
  if (i == 0) {
    for (int g = 0; g <= b; ++g) gstart[g] = 0;
  } else {
    int prev = batch[i - 1];
    for (int g = prev + 1; g <= b; ++g) gstart[g] = i;  // covers empty graphs too
  }
}

// ---------------- layer kernels ----------------

// layer-0 linear: [N,4] @ [4,128] -> hout (no bias; bias added in aggregate)
__global__ void k_mm0(const float* __restrict__ x, const float* __restrict__ W0,
                      float* __restrict__ hout) {
  int idx = blockIdx.x * 256 + threadIdx.x;
  if (idx >= NN * 128) return;
  int node = idx >> 7, j = idx & 127;
  const float* xr = x + node * 4;
  float s = xr[0] * W0[j];
  s = fmaf(xr[1], W0[128 + j], s);
  s = fmaf(xr[2], W0[256 + j], s);
  s = fmaf(xr[3], W0[384 + j], s);
  hout[idx] = s;
}

// [N,128] @ [128,128], relu applied to the INPUT (prev layer pre-activation)
__global__ __launch_bounds__(256) void k_mm128(const float* __restrict__ hin,
                                               const float* __restrict__ W,
                                               float* __restrict__ hout) {
  __shared__ float As[64][128];   // 32 KB: full K for 64 rows
  int tid = threadIdx.x;
  int row0 = blockIdx.x * 64;
  #pragma unroll
  for (int t = 0; t < 8; ++t) {
    int idx = t * 1024 + tid * 4;     // 0..8191
    int r = idx >> 7, c = idx & 127;
    int gr = row0 + r;
    float4 v = make_float4(0.f, 0.f, 0.f, 0.f);
    if (gr < NN) v = *(const float4*)(hin + gr * 128 + c);
    v.x = fmaxf(v.x, 0.f); v.y = fmaxf(v.y, 0.f);
    v.z = fmaxf(v.z, 0.f); v.w = fmaxf(v.w, 0.f);
    *(float4*)&As[r][c] = v;
  }
  __syncthreads();
  int ct = tid & 31;      // 32 col-threads * 4 cols = 128 cols
  int rt = tid >> 5;      // 8 row groups * 8 rows = 64 rows
  float acc[8][4];
  #pragma unroll
  for (int i = 0; i < 8; ++i)
    #pragma unroll
    for (int j = 0; j < 4; ++j) acc[i][j] = 0.f;
  #pragma unroll 4
  for (int k = 0; k < 128; ++k) {
    float4 b = *(const float4*)(W + k * 128 + ct * 4);  // coalesced, L1/L2-hot
    #pragma unroll
    for (int i = 0; i < 8; ++i) {
      float a = As[rt * 8 + i][k];   // 2 addrs/wave on one bank = free 2-way
      acc[i][0] = fmaf(a, b.x, acc[i][0]);
      acc[i][1] = fmaf(a, b.y, acc[i][1]);
      acc[i][2] = fmaf(a, b.z, acc[i][2]);
      acc[i][3] = fmaf(a, b.w, acc[i][3]);
    }
  }
  #pragma unroll
  for (int i = 0; i < 8; ++i) {
    int gr = row0 + rt * 8 + i;
    if (gr < NN)
      *(float4*)(hout + gr * 128 + ct * 4) =
          make_float4(acc[i][0], acc[i][1], acc[i][2], acc[i][3]);
  }
}

// out[i] = b + dinv[i]^2 * hlin[i] + sum_e w[e] * hlin[csr_src[e]]
// one wave per node, float2 per lane (64*2 = 128 cols).
// Edge metadata loaded cooperatively (one coalesced load per <=64-edge chunk),
// broadcast via v_readlane (SGPR), gathers unrolled x4 for 4 loads in flight.
__global__ __launch_bounds__(256) void k_aggregate(const float* __restrict__ hlin,
                                                   const int* __restrict__ rowptr,
                                                   const int* __restrict__ csr_src,
                                                   const float* __restrict__ csr_w,
                                                   const float* __restrict__ dinv,
                                                   const float* __restrict__ bias,
                                                   float* __restrict__ hout) {
  int node = blockIdx.x * 4 + (threadIdx.x >> 6);
  int lane = threadIdx.x & 63;
  if (node >= NN) return;
  float di = dinv[node];
  float sw = di * di;
  float2 hv = *(const float2*)(hlin + (size_t)node * 128 + lane * 2);
  float2 bv = *(const float2*)(bias + lane * 2);
  float2 acc = make_float2(fmaf(sw, hv.x, bv.x), fmaf(sw, hv.y, bv.y));
  int beg = rowptr[node], end = rowptr[node + 1];
  for (int base = beg; base < end; base += 64) {
    int m = end - base; if (m > 64) m = 64;           // wave-uniform
    int li = base + (lane < m ? lane : m - 1);        // clamp keeps loads in-bounds
    int idxv = csr_src[li];                           // one coalesced load / chunk
    int wbits = __float_as_int(csr_w[li]);
    int j = 0;
    for (; j + 4 <= m; j += 4) {                      // 4 gathers in flight
      int s0 = __builtin_amdgcn_readlane(idxv, j + 0);
      int s1 = __builtin_amdgcn_readlane(idxv, j + 1);
      int s2 = __builtin_amdgcn_readlane(idxv, j + 2);
      int s3 = __builtin_amdgcn_readlane(idxv, j + 3);
      float w0 = __int_as_float(__builtin_amdgcn_readlane(wbits, j + 0));
      float w1 = __int_as_float(__builtin_amdgcn_readlane(wbits, j + 1));
      float w2 = __int_as_float(__builtin_amdgcn_readlane(wbits, j + 2));
      float w3 = __int_as_float(__builtin_amdgcn_readlane(wbits, j + 3));
      float2 v0 = *(const float2*)(hlin + (size_t)s0 * 128 + lane * 2);
      float2 v1 = *(const float2*)(hlin + (size_t)s1 * 128 + lane * 2);
      float2 v2 = *(const float2*)(hlin + (size_t)s2 * 128 + lane * 2);
      float2 v3 = *(const float2*)(hlin + (size_t)s3 * 128 + lane * 2);
      acc.x = fmaf(w0, v0.x, acc.x); acc.y = fmaf(w0, v0.y, acc.y);
      acc.x = fmaf(w1, v1.x, acc.x); acc.y = fmaf(w1, v1.y, acc.y);
      acc.x = fmaf(w2, v2.x, acc.x); acc.y = fmaf(w2, v2.y, acc.y);
      acc.x = fmaf(w3, v3.x, acc.x); acc.y = fmaf(w3, v3.y, acc.y);
    }
    if (j + 2 <= m) {                                 // uniform-branch pair tail
      int s0 = __builtin_amdgcn_readlane(idxv, j + 0);
      int s1 = __builtin_amdgcn_readlane(idxv, j + 1);
      float w0 = __int_as_float(__builtin_amdgcn_readlane(wbits, j + 0));
      float w1 = __int_as_float(__builtin_amdgcn_readlane(wbits, j + 1));
      float2 v0 = *(const float2*)(hlin + (size_t)s0 * 128 + lane * 2);
      float2 v1 = *(const float2*)(hlin + (size_t)s1 * 128 + lane * 2);
      acc.x = fmaf(w0, v0.x, acc.x); acc.y = fmaf(w0, v0.y, acc.y);
      acc.x = fmaf(w1, v1.x, acc.x); acc.y = fmaf(w1, v1.y, acc.y);
      j += 2;
    }
    if (j < m) {                                      // uniform-branch single tail
      int s0 = __builtin_amdgcn_readlane(idxv, j);
      float w0 = __int_as_float(__builtin_amdgcn_readlane(wbits, j));
      float2 v0 = *(const float2*)(hlin + (size_t)s0 * 128 + lane * 2);
      acc.x = fmaf(w0, v0.x, acc.x); acc.y = fmaf(w0, v0.y, acc.y);
    }
  }
  *(float2*)(hout + (size_t)node * 128 + lane * 2) = acc;
}

// ---------------- fused pool (segmented, no atomics) + MLP head ----------------
// one block per graph; batch is sorted so nodes [gstart[g], gstart[g+1]) belong to g
__global__ __launch_bounds__(256) void k_poolmlp(const float* __restrict__ h4,
                                                 const int* __restrict__ gstart,
                                                 const float* __restrict__ xs,
                                                 const float* __restrict__ Wl1,
                                                 const float* __restrict__ bl1,
                                                 const float* __restrict__ Wl2,
                                                 const float* __restrict__ bl2,
                                                 float* __restrict__ out) {
  __shared__ float4 part[8][32];
  __shared__ float pooled[128];
  int g = blockIdx.x;
  int beg = gstart[g], end = gstart[g + 1];
  int tid = threadIdx.x;
  int cg = tid & 31;        // float4 column group (32 * 4 = 128 cols)
  int rg = tid >> 5;        // 8 rows per iteration
  float4 acc = make_float4(0.f, 0.f, 0.f, 0.f);
  for (int i = beg + rg; i < end; i += 8) {
    float4 v = *(const float4*)(h4 + (size_t)i * 128 + cg * 4);  // 4KB/iter coalesced
    acc.x += fmaxf(v.x, 0.f); acc.y += fmaxf(v.y, 0.f);
    acc.z += fmaxf(v.z, 0.f); acc.w += fmaxf(v.w, 0.f);
  }
  part[rg][cg] = acc;
  __syncthreads();
  if (tid < 32) {
    float4 s = part[0][tid];
    #pragma unroll
    for (int r = 1; r < 8; ++r) {
      float4 v = part[r][tid];
      s.x += v.x; s.y += v.y; s.z += v.z; s.w += v.w;
    }
    float sc = 1.f / fmaxf((float)(end - beg), 1.f);
    pooled[tid * 4 + 0] = s.x * sc;
    pooled[tid * 4 + 1] = s.y * sc;
    pooled[tid * 4 + 2] = s.z * sc;
    pooled[tid * 4 + 3] = s.w * sc;
  }
  __syncthreads();
  if (tid < 64) {   // exactly wave 0
    float hj = bl1[tid];
    #pragma unroll 4
    for (int k = 0; k < 128; ++k) hj = fmaf(pooled[k], Wl1[k * 64 + tid], hj);
    const float* xr = xs + g * 4;
    #pragma unroll
    for (int k = 0; k < 4; ++k) hj = fmaf(xr[k], Wl1[(128 + k) * 64 + tid], hj);
    hj = fmaxf(hj, 0.f);
    float val = hj * Wl2[tid];
    #pragma unroll
    for (int off = 32; off > 0; off >>= 1) val += __shfl_down(val, off);
    if (tid == 0) out[g] = val + bl2[0];
  }
}

// ---------------- launcher ----------------

extern "C" void kernel_launch(void* const* d_in, const int* in_sizes, int n_in,
                              void* d_out, int out_size, void* d_ws, size_t ws_size,
                              hipStream_t stream) {
  const float* x    = (const float*)d_in[0];
  const int*   ei   = (const int*)d_in[1];
  const float* xs   = (const float*)d_in[2];
  const int*   batch= (const int*)d_in[3];
  const float* W0   = (const float*)d_in[4];
  const float* b0   = (const float*)d_in[5];
  const float* W1   = (const float*)d_in[6];
  const float* b1   = (const float*)d_in[7];
  const float* W2   = (const float*)d_in[8];
  const float* b2   = (const float*)d_in[9];
  const float* W3   = (const float*)d_in[10];
  const float* b3   = (const float*)d_in[11];
  const float* Wl1  = (const float*)d_in[12];
  const float* bl1  = (const float*)d_in[13];
  const float* Wl2  = (const float*)d_in[14];
  const float* bl2  = (const float*)d_in[15];
  const int* srcA = ei;        // edge_index[0]
  const int* dstA = ei + EE;   // edge_index[1]
  float* out = (float*)d_out;

  char* p = (char*)d_ws;
  auto take = [&](size_t bytes) { char* q = p; p += (bytes + 255) & ~(size_t)255; return q; };
  float* hA    = (float*)take((size_t)NN * 128 * 4);
  float* hB    = (float*)take((size_t)NN * 128 * 4);
  int*   cnt   = (int*)take((size_t)NN * 4);
  float* dinv  = (float*)take((size_t)NN * 4);
  int*   rowptr= (int*)take((size_t)(NN + 1) * 4);
  int*   fillc = (int*)take((size_t)NN * 4);
  int*   csr_s = (int*)take((size_t)EE * 4);
  float* csr_w = (float*)take((size_t)EE * 4);
  int*   bsum  = (int*)take(512 * 4);
  int*   gstart= (int*)take((size_t)(GG + 1) * 4);

  // setup: degree, norm, CSR-by-dst, graph boundaries
  k_init<<<NB, 256, 0, stream>>>(cnt, fillc, gstart);
  k_count<<<(EE + 255) / 256, 256, 0, stream>>>(dstA, cnt);
  k_dinv<<<NB, 256, 0, stream>>>(cnt, dinv);
  k_scan1<<<NB, 256, 0, stream>>>(cnt, rowptr, bsum);
  k_scan2<<<1, 512, 0, stream>>>(bsum);
  k_scan3<<<NB, 256, 0, stream>>>(rowptr, bsum);
  k_fill<<<(EE + 255) / 256, 256, 0, stream>>>(srcA, dstA, rowptr, fillc, dinv, csr_s, csr_w);
  k_gbound<<<NB, 256, 0, stream>>>(batch, gstart);

  // layer 0: x @ W0 -> hA; aggregate(hA) + b0 -> hB (pre-relu)
  k_mm0<<<(NN * 128 + 255) / 256, 256, 0, stream>>>(x, W0, hA);
  k_aggregate<<<(NN + 3) / 4, 256, 0, stream>>>(hA, rowptr, csr_s, csr_w, dinv, b0, hB);
  // layers 1-3: relu fused into matmul A-load
  k_mm128<<<(NN + 63) / 64, 256, 0, stream>>>(hB, W1, hA);
  k_aggregate<<<(NN + 3) / 4, 256, 0, stream>>>(hA, rowptr, csr_s, csr_w, dinv, b1, hB);
  k_mm128<<<(NN + 63) / 64, 256, 0, stream>>>(hB, W2, hA);
  k_aggregate<<<(NN + 3) / 4, 256, 0, stream>>>(hA, rowptr, csr_s, csr_w, dinv, b2, hB);
  k_mm128<<<(NN + 63) / 64, 256, 0, stream>>>(hB, W3, hA);
  k_aggregate<<<(NN + 3) / 4, 256, 0, stream>>>(hA, rowptr, csr_s, csr_w, dinv, b3, hB);

  // fused pool + head MLP (no atomics)
  k_poolmlp<<<GG, 256, 0, stream>>>(hB, gstart, xs, Wl1, bl1, Wl2, bl2, out);
}